// Round 6
// baseline (423.161 us; speedup 1.0000x reference)
//
#include <hip/hip_runtime.h>

// out[r,f] = bias[f] + sum_{i: rows[i]==r} value[i] * weight[cols[i], f]
// Pipeline: per-chunk histograms (kA) -> parallel reduce (kB1) -> scan +
// deterministic per-(chunk,coarse) offsets (kB2) -> ATOMIC-FREE coarse bin
// (kC) -> fine bin, 2KB runs (kD) -> per-bucket LDS sort + register-FMA
// consumer (k_spmm4, 38.4 KB LDS = 4 blocks/CU, grid 1024 = one round).
// R5 post-mortem: consumer had 3 blocks/CU -> 2 rounds for 1024 blocks (tail);
// binning ~140us suspected on cursorC global-atomic line contention.
//
// pair pack (u64): val[63:32] | fine[29:20] | lr[19:13] | col[12:0]

#define NBF 1024
#define DMAX 128     // lr 7 bits => d <= 128 (n <= 131072)
#define CH 4096      // binning chunk
#define C2 4096      // bin2 chunk
#define CC 1536      // consumer sort chunk
#define SP_T 512

__global__ void k_zero1024(int* __restrict__ p) { p[threadIdx.x] = 0; }

// Per-chunk fine (1024) + coarse (64) histograms, written per-block (no
// global atomics). Chunk mapping MUST match kC_bin1.
__global__ __launch_bounds__(512) void kA_hist(const int* __restrict__ rows, int nnz,
        unsigned M, int S, int* __restrict__ hist2dF, int* __restrict__ hist2dC) {
    __shared__ int h[NBF];
    int t = threadIdx.x, blk = blockIdx.x;
    long long base = (long long)blk * CH;
    int count = (int)min((long long)CH, (long long)nnz - base);
    h[t] = 0; h[t + 512] = 0;
    __syncthreads();
#pragma unroll
    for (int k = 0; k < 8; ++k) {
        int i = t + (k << 9);
        if (i < count) {
            unsigned r = (unsigned)rows[base + i];
            int f = (int)(((unsigned long long)r * M) >> S);
            atomicAdd(&h[f], 1);
        }
    }
    __syncthreads();
    hist2dF[blk * NBF + t] = h[t];
    hist2dF[blk * NBF + 512 + t] = h[t + 512];
    if (t < 64) {
        int s = 0;
#pragma unroll
        for (int j = 0; j < 16; ++j) s += h[(t << 4) + j];
        hist2dC[(blk << 6) + t] = s;
    }
}

// Parallel column-reduce hist2dF -> gcnt (64 partial atomics per counter).
__global__ __launch_bounds__(1024) void kB1_reduce(const int* __restrict__ hist2dF,
        int nChunks, int* __restrict__ gcnt) {
    int t = threadIdx.x;
    int s = 0;
    for (int b = blockIdx.x; b < nChunks; b += gridDim.x) s += hist2dF[b * NBF + t];
    if (s) atomicAdd(&gcnt[t], s);
}

// Single block: scan gcnt -> fineBase/cursorF; optional deterministic
// per-(chunk,coarse) absolute offsets (serial over chunks, 64 lanes).
__global__ __launch_bounds__(1024) void kB2_scan(const int* __restrict__ gcnt,
        const int* __restrict__ hist2dC, int nChunks, int* __restrict__ fineBase,
        int* __restrict__ cursorF, int* __restrict__ blockOffC, int doOff) {
    __shared__ int sE[NBF];
    __shared__ int wsum[16];
    int t = threadIdx.x, lane = t & 63, wv = t >> 6;
    int v = gcnt[t];
    int x = v;
#pragma unroll
    for (int off = 1; off < 64; off <<= 1) {
        int y = __shfl_up(x, off, 64);
        if (lane >= off) x += y;
    }
    if (lane == 63) wsum[wv] = x;
    __syncthreads();
    if (t < 16) {
        int s = wsum[t], xs = s;
#pragma unroll
        for (int off = 1; off < 16; off <<= 1) {
            int y = __shfl_up(xs, off, 16);
            if (t >= off) xs += y;
        }
        wsum[t] = xs - s;
    }
    __syncthreads();
    int incl = x + wsum[wv], excl = incl - v;
    fineBase[t] = excl;
    cursorF[t] = excl;
    sE[t] = excl;
    if (t == NBF - 1) fineBase[NBF] = incl;
    __syncthreads();
    if (doOff && t < 64) {
        int running = sE[t << 4];
        for (int b = 0; b < nChunks; ++b) {
            blockOffC[(b << 6) + t] = running;
            running += hist2dC[(b << 6) + t];
        }
    }
}

// Path3 fallback: grid-stride fine histogram with global atomics.
__global__ void k_ghist(const int* __restrict__ rows, int nnz, unsigned M, int S,
                        int* __restrict__ gcnt) {
    __shared__ int h[NBF];
    int t = threadIdx.x;
    for (int i = t; i < NBF; i += blockDim.x) h[i] = 0;
    __syncthreads();
    for (int i = blockIdx.x * blockDim.x + t; i < nnz; i += gridDim.x * blockDim.x) {
        unsigned r = (unsigned)rows[i];
        int f = (int)(((unsigned long long)r * M) >> S);
        atomicAdd(&h[f], 1);
    }
    __syncthreads();
    for (int i = t; i < NBF; i += blockDim.x)
        if (h[i]) atomicAdd(&gcnt[i], h[i]);
}

// Coarse bin, ATOMIC-FREE: dest base from precomputed blockOffC. Runs ~512 B.
__global__ __launch_bounds__(512) void kC_bin1(const int* __restrict__ rows,
        const int* __restrict__ cols, const float* __restrict__ vals, int nnz,
        unsigned M, int S, int d, const int* __restrict__ blockOffC,
        unsigned long long* __restrict__ pairs1) {
    __shared__ unsigned long long stage[CH];  // 32 KB
    __shared__ int histC[64], scC[64], adjC[64];
    int t = threadIdx.x, blk = blockIdx.x;
    long long base = (long long)blk * CH;
    int count = (int)min((long long)CH, (long long)nnz - base);
    if (t < 64) histC[t] = 0;
    __syncthreads();
    int cs8[8], rk8[8];
    unsigned long long pk8[8];
#pragma unroll
    for (int k = 0; k < 8; ++k) {
        int i = t + (k << 9);
        cs8[k] = -1;
        if (i < count) {
            unsigned r = (unsigned)rows[base + i];
            int c = cols[base + i];
            float v = vals[base + i];
            int f = (int)(((unsigned long long)r * M) >> S);
            int lr = (int)r - f * d;
            int cs = f >> 4;
            cs8[k] = cs;
            rk8[k] = atomicAdd(&histC[cs], 1);
            pk8[k] = ((unsigned long long)__float_as_uint(v) << 32) |
                     ((unsigned)f << 20) | ((unsigned)lr << 13) | (unsigned)c;
        }
    }
    __syncthreads();
    if (t < 64) {
        int v = histC[t], x = v;
#pragma unroll
        for (int off = 1; off < 64; off <<= 1) {
            int y = __shfl_up(x, off, 64);
            if (t >= off) x += y;
        }
        scC[t] = x;
        adjC[t] = blockOffC[(blk << 6) + t] - (x - v);  // no atomic
    }
    __syncthreads();
#pragma unroll
    for (int k = 0; k < 8; ++k)
        if (cs8[k] >= 0) stage[(scC[cs8[k]] - histC[cs8[k]]) + rk8[k]] = pk8[k];
    __syncthreads();
    for (int i = t; i < count; i += 512) {
        unsigned long long p = stage[i];
        int cs = (int)((p >> 24) & 63);
        pairs1[adjC[cs] + i] = p;
    }
}

// Fine bin from coarse-sorted pairs; ~16 fine ids per chunk -> 2 KB runs.
// cursorF atomics: ~16 per counter (harmless).
__global__ __launch_bounds__(1024) void kD_bin2(const unsigned long long* __restrict__ pairs1,
        int nnz, int* __restrict__ cursorF, unsigned long long* __restrict__ pairs2) {
    __shared__ unsigned long long stage[C2];  // 32 KB
    __shared__ int histF[NBF], scF[NBF], adjF[NBF];
    __shared__ int wsum[16];
    int t = threadIdx.x, lane = t & 63, wv = t >> 6;
    long long base = (long long)blockIdx.x * C2;
    int count = (int)min((long long)C2, (long long)nnz - base);
    histF[t] = 0;
    __syncthreads();
    int f4[4], rk4[4];
    unsigned long long pk4[4];
#pragma unroll
    for (int k = 0; k < 4; ++k) {
        int i = t + (k << 10);
        f4[k] = -1;
        if (i < count) {
            unsigned long long p = pairs1[base + i];
            int f = (int)((p >> 20) & 1023);
            f4[k] = f;
            rk4[k] = atomicAdd(&histF[f], 1);
            pk4[k] = p;
        }
    }
    __syncthreads();
    int v = histF[t], x = v;
#pragma unroll
    for (int off = 1; off < 64; off <<= 1) {
        int y = __shfl_up(x, off, 64);
        if (lane >= off) x += y;
    }
    if (lane == 63) wsum[wv] = x;
    __syncthreads();
    if (t < 16) {
        int s = wsum[t], xs = s;
#pragma unroll
        for (int off = 1; off < 16; off <<= 1) {
            int y = __shfl_up(xs, off, 16);
            if (t >= off) xs += y;
        }
        wsum[t] = xs - s;
    }
    __syncthreads();
    int incl = x + wsum[wv];
    scF[t] = incl;
    if (v > 0) {
        int g = atomicAdd(&cursorF[t], v);
        adjF[t] = g - (incl - v);
    }
    __syncthreads();
#pragma unroll
    for (int k = 0; k < 4; ++k)
        if (f4[k] >= 0) stage[(scF[f4[k]] - histF[f4[k]]) + rk4[k]] = pk4[k];
    __syncthreads();
    for (int i = t; i < count; i += 1024) {
        unsigned long long p = stage[i];
        int f = (int)((p >> 20) & 1023);
        pairs2[adjF[f] + i] = p;
    }
}

// Fallback direct fine bin (paths 2/3): source -> fine buckets, cursorF atomics.
__global__ __launch_bounds__(1024) void k_bin_direct(const int* __restrict__ rows,
        const int* __restrict__ cols, const float* __restrict__ vals, int nnz,
        unsigned M, int S, int d, int* __restrict__ cursorF,
        unsigned long long* __restrict__ pairs1) {
    __shared__ unsigned long long stage[C2];
    __shared__ int histF[NBF], scF[NBF], adjF[NBF];
    __shared__ int wsum[16];
    int t = threadIdx.x, lane = t & 63, wv = t >> 6;
    long long base = (long long)blockIdx.x * C2;
    int count = (int)min((long long)C2, (long long)nnz - base);
    histF[t] = 0;
    __syncthreads();
    int f4[4], rk4[4];
    unsigned long long pk4[4];
#pragma unroll
    for (int k = 0; k < 4; ++k) {
        int i = t + (k << 10);
        f4[k] = -1;
        if (i < count) {
            unsigned r = (unsigned)rows[base + i];
            int c = cols[base + i];
            float vv = vals[base + i];
            int f = (int)(((unsigned long long)r * M) >> S);
            int lr = (int)r - f * d;
            f4[k] = f;
            rk4[k] = atomicAdd(&histF[f], 1);
            pk4[k] = ((unsigned long long)__float_as_uint(vv) << 32) |
                     ((unsigned)f << 20) | ((unsigned)lr << 13) | (unsigned)c;
        }
    }
    __syncthreads();
    int v = histF[t], x = v;
#pragma unroll
    for (int off = 1; off < 64; off <<= 1) {
        int y = __shfl_up(x, off, 64);
        if (lane >= off) x += y;
    }
    if (lane == 63) wsum[wv] = x;
    __syncthreads();
    if (t < 16) {
        int s = wsum[t], xs = s;
#pragma unroll
        for (int off = 1; off < 16; off <<= 1) {
            int y = __shfl_up(xs, off, 16);
            if (t >= off) xs += y;
        }
        wsum[t] = xs - s;
    }
    __syncthreads();
    int incl = x + wsum[wv];
    scF[t] = incl;
    if (v > 0) {
        int g = atomicAdd(&cursorF[t], v);
        adjF[t] = g - (incl - v);
    }
    __syncthreads();
#pragma unroll
    for (int k = 0; k < 4; ++k)
        if (f4[k] >= 0) stage[(scF[f4[k]] - histF[f4[k]]) + rk4[k]] = pk4[k];
    __syncthreads();
    for (int i = t; i < count; i += 1024) {
        unsigned long long p = stage[i];
        int f = (int)((p >> 20) & 1023);
        pairs1[adjF[f] + i] = p;
    }
}

// Consumer: one block per fine bucket, 38.4 KB LDS => 4 blocks/CU, grid 1024
// = exactly one scheduling round. Sort chunk by local row (int LDS atomics +
// shfl scan), then 16-lane groups walk whole rows with register float4 FMA.
__global__ __launch_bounds__(SP_T, 8) void k_spmm4(
        const unsigned long long* __restrict__ pairs, const int* __restrict__ fineBase,
        const float* __restrict__ weight, const float* __restrict__ bias,
        float* __restrict__ out, int d, int n) {
    __shared__ unsigned long long stage[CC];   // 12 KB
    __shared__ int histR[DMAX], scR[DMAX];     // 1 KB
    extern __shared__ float acc[];             // d*64 floats (25 KB @ d=98)
    int b = blockIdx.x, t = threadIdx.x;
    int row0 = b * d;
    if (row0 >= n) return;
    int nrows = min(d, n - row0);
    int start = fineBase[b], end = fineBase[b + 1];

    for (int i = t; i < (nrows << 6); i += SP_T) acc[i] = 0.0f;

    int g = t >> 4, fq = t & 15;
    for (int cb = start; cb < end; cb += CC) {
        int cnt = min(CC, end - cb);
        if (t < DMAX) histR[t] = 0;
        __syncthreads();
        int lr3[3], rk3[3];
        unsigned long long pk3[3];
#pragma unroll
        for (int k = 0; k < 3; ++k) {
            int i = t + (k << 9);
            lr3[k] = -1;
            if (i < cnt) {
                unsigned long long p = pairs[cb + i];
                int lr = (int)((p >> 13) & 127);
                lr3[k] = lr;
                rk3[k] = atomicAdd(&histR[lr], 1);
                pk3[k] = p;
            }
        }
        __syncthreads();
        if (t < DMAX) {
            int v = histR[t], x = v;
            int lane = t & 63;
#pragma unroll
            for (int off = 1; off < 64; off <<= 1) {
                int y = __shfl_up(x, off, 64);
                if (lane >= off) x += y;
            }
            scR[t] = x;
        }
        __syncthreads();
        if (t >= 64 && t < DMAX) scR[t] += scR[63];
        __syncthreads();
#pragma unroll
        for (int k = 0; k < 3; ++k)
            if (lr3[k] >= 0) stage[(scR[lr3[k]] - histR[lr3[k]]) + rk3[k]] = pk3[k];
        __syncthreads();

        for (int r = g; r < nrows; r += 32) {
            int e = scR[r], s = e - histR[r];
            if (s >= e) continue;
            float4 a = {0.0f, 0.0f, 0.0f, 0.0f};
#pragma unroll 2
            for (int j = s; j < e; ++j) {
                unsigned long long p = stage[j];
                int c = (int)(p & 8191);
                float vv = __uint_as_float((unsigned)(p >> 32));
                const float4 w = *(const float4*)(weight + (c << 6) + (fq << 2));
                a.x = fmaf(vv, w.x, a.x);
                a.y = fmaf(vv, w.y, a.y);
                a.z = fmaf(vv, w.z, a.z);
                a.w = fmaf(vv, w.w, a.w);
            }
            float4* ap = (float4*)&acc[(r << 6) + (fq << 2)];
            float4 o = *ap;
            o.x += a.x; o.y += a.y; o.z += a.z; o.w += a.w;
            *ap = o;
        }
        __syncthreads();
    }

    for (int i = t; i < (nrows << 6); i += SP_T)
        out[((long long)row0 << 6) + i] = acc[i] + bias[i & 63];
}

extern "C" void kernel_launch(void* const* d_in, const int* in_sizes, int n_in,
                              void* d_out, int out_size, void* d_ws, size_t ws_size,
                              hipStream_t stream) {
    const int*   index  = (const int*)d_in[0];
    const float* value  = (const float*)d_in[1];
    const float* weight = (const float*)d_in[3];
    const float* bias   = (const float*)d_in[4];
    float*       out    = (float*)d_out;

    int nnz = in_sizes[0] / 2;
    int n   = out_size / 64;
    const int* rows = index;
    const int* cols = index + nnz;

    int d = (n + NBF - 1) / NBF;  // 98 for n=100000 (<= DMAX)
    unsigned M = 0;
    int S = 0;
    for (S = 20; S <= 40; ++S) {
        unsigned long long m = ((1ull << S) + (unsigned)d - 1) / (unsigned)d;
        unsigned long long e = m * (unsigned long long)d - (1ull << S);
        if (m <= 0xffffffffull && e * (unsigned long long)(n > 0 ? n - 1 : 0) < (1ull << S)) {
            M = (unsigned)m;
            break;
        }
    }

    int nChunks = (nnz + CH - 1) / CH;
    char* ws = (char*)d_ws;
    int* fineBase = (int*)ws;                 // 8 KB reserved
    int* cursorF  = (int*)(ws + (8 << 10));   // 4 KB
    int* gcnt     = (int*)(ws + (12 << 10));  // 4 KB
    size_t offC = 64 << 10;
    size_t szC  = (((size_t)nChunks * 64 * 4) + 255) & ~(size_t)255;
    size_t offO = offC + szC;                 // blockOffC
    size_t offF = offO + szC;                 // hist2dF
    size_t szF  = (((size_t)nChunks * NBF * 4) + 255) & ~(size_t)255;
    size_t offP1 = offF + szF;
    size_t szP   = (((size_t)nnz * 8) + 255) & ~(size_t)255;
    size_t offP2 = offP1 + szP;
    int* hist2dC   = (int*)(ws + offC);
    int* blockOffC = (int*)(ws + offO);
    int* hist2dF   = (int*)(ws + offF);
    unsigned long long* pairs1 = (unsigned long long*)(ws + offP1);
    unsigned long long* pairs2 = (unsigned long long*)(ws + offP2);
    unsigned long long* pairs3 = (unsigned long long*)(ws + offC);  // path3 overlay

    bool two = ws_size >= offP2 + szP;
    bool dir = !two && ws_size >= offP1 + szP;

    k_zero1024<<<1, 1024, 0, stream>>>(gcnt);
    size_t smem = (size_t)d * 64 * sizeof(float);
    int spGrid = (n + d - 1) / d;  // 1021 -> pad to NBF grid? exact buckets
    if (two || dir) {
        kA_hist<<<nChunks, 512, 0, stream>>>(rows, nnz, M, S, hist2dF, hist2dC);
        kB1_reduce<<<64, 1024, 0, stream>>>(hist2dF, nChunks, gcnt);
        kB2_scan<<<1, 1024, 0, stream>>>(gcnt, hist2dC, nChunks, fineBase, cursorF,
                                         blockOffC, two ? 1 : 0);
        if (two) {
            kC_bin1<<<nChunks, 512, 0, stream>>>(rows, cols, value, nnz, M, S, d,
                                                 blockOffC, pairs1);
            kD_bin2<<<nChunks, 1024, 0, stream>>>(pairs1, nnz, cursorF, pairs2);
            k_spmm4<<<NBF, SP_T, smem, stream>>>(pairs2, fineBase, weight, bias, out, d, n);
        } else {
            k_bin_direct<<<nChunks, 1024, 0, stream>>>(rows, cols, value, nnz, M, S, d,
                                                       cursorF, pairs1);
            k_spmm4<<<NBF, SP_T, smem, stream>>>(pairs1, fineBase, weight, bias, out, d, n);
        }
    } else {
        k_ghist<<<256, 512, 0, stream>>>(rows, nnz, M, S, gcnt);
        kB2_scan<<<1, 1024, 0, stream>>>(gcnt, hist2dC, nChunks, fineBase, cursorF,
                                         blockOffC, 0);
        k_bin_direct<<<nChunks, 1024, 0, stream>>>(rows, cols, value, nnz, M, S, d,
                                                   cursorF, pairs3);
        k_spmm4<<<NBF, SP_T, smem, stream>>>(pairs3, fineBase, weight, bias, out, d, n);
    }
    (void)spGrid;
}

// Round 7
// 188.932 us; speedup vs baseline: 2.2398x; 2.2398x over previous
//
#include <hip/hip_runtime.h>

// out[r,f] = bias[f] + sum_{i: rows[i]==r} value[i] * weight[cols[i], f]
// Pipeline: per-chunk histograms (kA) -> reduce (kB1) -> fine scan (kB2) ->
// PARALLEL per-(chunk,coarse) offset scan (kB3, 64 blocks x 1024-thread
// shfl scan; replaces R6's serial 245us single-wave loop) -> atomic-free
// coarse bin (kC) -> fine bin 2KB runs (kD) -> per-bucket LDS sort +
// register-FMA consumer (k_spmm4, 38.4 KB LDS = 4 blocks/CU).
//
// pair pack (u64): val[63:32] | fine[29:20] | lr[19:13] | col[12:0]

#define NBF 1024
#define DMAX 128     // lr 7 bits => d <= 128 (n <= 131072)
#define CH 4096      // binning chunk
#define C2 4096      // bin2 chunk
#define CC 1536      // consumer sort chunk
#define SP_T 512

__global__ void k_zero1024(int* __restrict__ p) { p[threadIdx.x] = 0; }

// Per-chunk fine (1024) + coarse (64) histograms, per-block writes (no
// global atomics). Chunk mapping MUST match kC_bin1.
__global__ __launch_bounds__(512) void kA_hist(const int* __restrict__ rows, int nnz,
        unsigned M, int S, int* __restrict__ hist2dF, int* __restrict__ hist2dC) {
    __shared__ int h[NBF];
    int t = threadIdx.x, blk = blockIdx.x;
    long long base = (long long)blk * CH;
    int count = (int)min((long long)CH, (long long)nnz - base);
    h[t] = 0; h[t + 512] = 0;
    __syncthreads();
#pragma unroll
    for (int k = 0; k < 8; ++k) {
        int i = t + (k << 9);
        if (i < count) {
            unsigned r = (unsigned)rows[base + i];
            int f = (int)(((unsigned long long)r * M) >> S);
            atomicAdd(&h[f], 1);
        }
    }
    __syncthreads();
    hist2dF[blk * NBF + t] = h[t];
    hist2dF[blk * NBF + 512 + t] = h[t + 512];
    if (t < 64) {
        int s = 0;
#pragma unroll
        for (int j = 0; j < 16; ++j) s += h[(t << 4) + j];
        hist2dC[(blk << 6) + t] = s;
    }
}

// Parallel column-reduce hist2dF -> gcnt.
__global__ __launch_bounds__(1024) void kB1_reduce(const int* __restrict__ hist2dF,
        int nChunks, int* __restrict__ gcnt) {
    int t = threadIdx.x;
    int s = 0;
    for (int b = blockIdx.x; b < nChunks; b += gridDim.x) s += hist2dF[b * NBF + t];
    if (s) atomicAdd(&gcnt[t], s);
}

// Single block: scan gcnt -> fineBase / cursorF. (No serial work.)
__global__ __launch_bounds__(1024) void kB2_scan(const int* __restrict__ gcnt,
        int* __restrict__ fineBase, int* __restrict__ cursorF) {
    __shared__ int wsum[16];
    int t = threadIdx.x, lane = t & 63, wv = t >> 6;
    int v = gcnt[t];
    int x = v;
#pragma unroll
    for (int off = 1; off < 64; off <<= 1) {
        int y = __shfl_up(x, off, 64);
        if (lane >= off) x += y;
    }
    if (lane == 63) wsum[wv] = x;
    __syncthreads();
    if (t < 16) {
        int s = wsum[t], xs = s;
#pragma unroll
        for (int off = 1; off < 16; off <<= 1) {
            int y = __shfl_up(xs, off, 16);
            if (t >= off) xs += y;
        }
        wsum[t] = xs - s;
    }
    __syncthreads();
    int incl = x + wsum[wv], excl = incl - v;
    fineBase[t] = excl;
    cursorF[t] = excl;
    if (t == NBF - 1) fineBase[NBF] = incl;
}

// Parallel per-(chunk,coarse) offsets: block c scans hist2dC[:, c] over the
// chunk axis (1024 elems/tile, shfl block scan, carry across tiles), seeded
// with fineBase[c*16]. 64 blocks. Replaces R6's serial single-wave loop.
__global__ __launch_bounds__(1024) void kB3_off(const int* __restrict__ hist2dC,
        int nChunks, const int* __restrict__ fineBase, int* __restrict__ blockOffC) {
    __shared__ int wsum[16];
    __shared__ int totalSh;
    int c = blockIdx.x, t = threadIdx.x, lane = t & 63, wv = t >> 6;
    int carry = fineBase[c << 4];
    for (int base = 0; base < nChunks; base += 1024) {
        int idx = base + t;
        int v = (idx < nChunks) ? hist2dC[(idx << 6) + c] : 0;
        int x = v;
#pragma unroll
        for (int off = 1; off < 64; off <<= 1) {
            int y = __shfl_up(x, off, 64);
            if (lane >= off) x += y;
        }
        if (lane == 63) wsum[wv] = x;
        __syncthreads();
        if (t < 16) {
            int s = wsum[t], xs = s;
#pragma unroll
            for (int off = 1; off < 16; off <<= 1) {
                int y = __shfl_up(xs, off, 16);
                if (t >= off) xs += y;
            }
            wsum[t] = xs - s;
        }
        __syncthreads();
        int incl = x + wsum[wv];
        if (idx < nChunks) blockOffC[(idx << 6) + c] = carry + incl - v;
        if (t == 1023) totalSh = incl;
        __syncthreads();
        carry += totalSh;
    }
}

// Path3 fallback: grid-stride fine histogram with global atomics.
__global__ void k_ghist(const int* __restrict__ rows, int nnz, unsigned M, int S,
                        int* __restrict__ gcnt) {
    __shared__ int h[NBF];
    int t = threadIdx.x;
    for (int i = t; i < NBF; i += blockDim.x) h[i] = 0;
    __syncthreads();
    for (int i = blockIdx.x * blockDim.x + t; i < nnz; i += gridDim.x * blockDim.x) {
        unsigned r = (unsigned)rows[i];
        int f = (int)(((unsigned long long)r * M) >> S);
        atomicAdd(&h[f], 1);
    }
    __syncthreads();
    for (int i = t; i < NBF; i += blockDim.x)
        if (h[i]) atomicAdd(&gcnt[i], h[i]);
}

// Coarse bin, ATOMIC-FREE: dest base from precomputed blockOffC. Runs ~512 B.
__global__ __launch_bounds__(512) void kC_bin1(const int* __restrict__ rows,
        const int* __restrict__ cols, const float* __restrict__ vals, int nnz,
        unsigned M, int S, int d, const int* __restrict__ blockOffC,
        unsigned long long* __restrict__ pairs1) {
    __shared__ unsigned long long stage[CH];  // 32 KB
    __shared__ int histC[64], scC[64], adjC[64];
    int t = threadIdx.x, blk = blockIdx.x;
    long long base = (long long)blk * CH;
    int count = (int)min((long long)CH, (long long)nnz - base);
    if (t < 64) histC[t] = 0;
    __syncthreads();
    int cs8[8], rk8[8];
    unsigned long long pk8[8];
#pragma unroll
    for (int k = 0; k < 8; ++k) {
        int i = t + (k << 9);
        cs8[k] = -1;
        if (i < count) {
            unsigned r = (unsigned)rows[base + i];
            int c = cols[base + i];
            float v = vals[base + i];
            int f = (int)(((unsigned long long)r * M) >> S);
            int lr = (int)r - f * d;
            int cs = f >> 4;
            cs8[k] = cs;
            rk8[k] = atomicAdd(&histC[cs], 1);
            pk8[k] = ((unsigned long long)__float_as_uint(v) << 32) |
                     ((unsigned)f << 20) | ((unsigned)lr << 13) | (unsigned)c;
        }
    }
    __syncthreads();
    if (t < 64) {
        int v = histC[t], x = v;
#pragma unroll
        for (int off = 1; off < 64; off <<= 1) {
            int y = __shfl_up(x, off, 64);
            if (t >= off) x += y;
        }
        scC[t] = x;
        adjC[t] = blockOffC[(blk << 6) + t] - (x - v);  // no atomic
    }
    __syncthreads();
#pragma unroll
    for (int k = 0; k < 8; ++k)
        if (cs8[k] >= 0) stage[(scC[cs8[k]] - histC[cs8[k]]) + rk8[k]] = pk8[k];
    __syncthreads();
    for (int i = t; i < count; i += 512) {
        unsigned long long p = stage[i];
        int cs = (int)((p >> 24) & 63);
        pairs1[adjC[cs] + i] = p;
    }
}

// Fine bin from coarse-sorted pairs; ~16-32 fine ids per chunk -> 2 KB runs.
__global__ __launch_bounds__(1024) void kD_bin2(const unsigned long long* __restrict__ pairs1,
        int nnz, int* __restrict__ cursorF, unsigned long long* __restrict__ pairs2) {
    __shared__ unsigned long long stage[C2];  // 32 KB
    __shared__ int histF[NBF], scF[NBF], adjF[NBF];
    __shared__ int wsum[16];
    int t = threadIdx.x, lane = t & 63, wv = t >> 6;
    long long base = (long long)blockIdx.x * C2;
    int count = (int)min((long long)C2, (long long)nnz - base);
    histF[t] = 0;
    __syncthreads();
    int f4[4], rk4[4];
    unsigned long long pk4[4];
#pragma unroll
    for (int k = 0; k < 4; ++k) {
        int i = t + (k << 10);
        f4[k] = -1;
        if (i < count) {
            unsigned long long p = pairs1[base + i];
            int f = (int)((p >> 20) & 1023);
            f4[k] = f;
            rk4[k] = atomicAdd(&histF[f], 1);
            pk4[k] = p;
        }
    }
    __syncthreads();
    int v = histF[t], x = v;
#pragma unroll
    for (int off = 1; off < 64; off <<= 1) {
        int y = __shfl_up(x, off, 64);
        if (lane >= off) x += y;
    }
    if (lane == 63) wsum[wv] = x;
    __syncthreads();
    if (t < 16) {
        int s = wsum[t], xs = s;
#pragma unroll
        for (int off = 1; off < 16; off <<= 1) {
            int y = __shfl_up(xs, off, 16);
            if (t >= off) xs += y;
        }
        wsum[t] = xs - s;
    }
    __syncthreads();
    int incl = x + wsum[wv];
    scF[t] = incl;
    if (v > 0) {
        int g = atomicAdd(&cursorF[t], v);
        adjF[t] = g - (incl - v);
    }
    __syncthreads();
#pragma unroll
    for (int k = 0; k < 4; ++k)
        if (f4[k] >= 0) stage[(scF[f4[k]] - histF[f4[k]]) + rk4[k]] = pk4[k];
    __syncthreads();
    for (int i = t; i < count; i += 1024) {
        unsigned long long p = stage[i];
        int f = (int)((p >> 20) & 1023);
        pairs2[adjF[f] + i] = p;
    }
}

// Fallback direct fine bin: source -> fine buckets, cursorF atomics.
__global__ __launch_bounds__(1024) void k_bin_direct(const int* __restrict__ rows,
        const int* __restrict__ cols, const float* __restrict__ vals, int nnz,
        unsigned M, int S, int d, int* __restrict__ cursorF,
        unsigned long long* __restrict__ pairs1) {
    __shared__ unsigned long long stage[C2];
    __shared__ int histF[NBF], scF[NBF], adjF[NBF];
    __shared__ int wsum[16];
    int t = threadIdx.x, lane = t & 63, wv = t >> 6;
    long long base = (long long)blockIdx.x * C2;
    int count = (int)min((long long)C2, (long long)nnz - base);
    histF[t] = 0;
    __syncthreads();
    int f4[4], rk4[4];
    unsigned long long pk4[4];
#pragma unroll
    for (int k = 0; k < 4; ++k) {
        int i = t + (k << 10);
        f4[k] = -1;
        if (i < count) {
            unsigned r = (unsigned)rows[base + i];
            int c = cols[base + i];
            float vv = vals[base + i];
            int f = (int)(((unsigned long long)r * M) >> S);
            int lr = (int)r - f * d;
            f4[k] = f;
            rk4[k] = atomicAdd(&histF[f], 1);
            pk4[k] = ((unsigned long long)__float_as_uint(vv) << 32) |
                     ((unsigned)f << 20) | ((unsigned)lr << 13) | (unsigned)c;
        }
    }
    __syncthreads();
    int v = histF[t], x = v;
#pragma unroll
    for (int off = 1; off < 64; off <<= 1) {
        int y = __shfl_up(x, off, 64);
        if (lane >= off) x += y;
    }
    if (lane == 63) wsum[wv] = x;
    __syncthreads();
    if (t < 16) {
        int s = wsum[t], xs = s;
#pragma unroll
        for (int off = 1; off < 16; off <<= 1) {
            int y = __shfl_up(xs, off, 16);
            if (t >= off) xs += y;
        }
        wsum[t] = xs - s;
    }
    __syncthreads();
    int incl = x + wsum[wv];
    scF[t] = incl;
    if (v > 0) {
        int g = atomicAdd(&cursorF[t], v);
        adjF[t] = g - (incl - v);
    }
    __syncthreads();
#pragma unroll
    for (int k = 0; k < 4; ++k)
        if (f4[k] >= 0) stage[(scF[f4[k]] - histF[f4[k]]) + rk4[k]] = pk4[k];
    __syncthreads();
    for (int i = t; i < count; i += 1024) {
        unsigned long long p = stage[i];
        int f = (int)((p >> 20) & 1023);
        pairs1[adjF[f] + i] = p;
    }
}

// Consumer: one block per fine bucket, 38.4 KB LDS => 4 blocks/CU. Sort chunk
// by local row (int LDS atomics + shfl scan), then 16-lane groups walk whole
// rows with register float4 FMA. No float atomics.
__global__ __launch_bounds__(SP_T, 8) void k_spmm4(
        const unsigned long long* __restrict__ pairs, const int* __restrict__ fineBase,
        const float* __restrict__ weight, const float* __restrict__ bias,
        float* __restrict__ out, int d, int n) {
    __shared__ unsigned long long stage[CC];   // 12 KB
    __shared__ int histR[DMAX], scR[DMAX];     // 1 KB
    extern __shared__ float acc[];             // d*64 floats (25 KB @ d=98)
    int b = blockIdx.x, t = threadIdx.x;
    int row0 = b * d;
    if (row0 >= n) return;
    int nrows = min(d, n - row0);
    int start = fineBase[b], end = fineBase[b + 1];

    for (int i = t; i < (nrows << 6); i += SP_T) acc[i] = 0.0f;

    int g = t >> 4, fq = t & 15;
    for (int cb = start; cb < end; cb += CC) {
        int cnt = min(CC, end - cb);
        if (t < DMAX) histR[t] = 0;
        __syncthreads();
        int lr3[3], rk3[3];
        unsigned long long pk3[3];
#pragma unroll
        for (int k = 0; k < 3; ++k) {
            int i = t + (k << 9);
            lr3[k] = -1;
            if (i < cnt) {
                unsigned long long p = pairs[cb + i];
                int lr = (int)((p >> 13) & 127);
                lr3[k] = lr;
                rk3[k] = atomicAdd(&histR[lr], 1);
                pk3[k] = p;
            }
        }
        __syncthreads();
        if (t < DMAX) {
            int v = histR[t], x = v;
            int lane = t & 63;
#pragma unroll
            for (int off = 1; off < 64; off <<= 1) {
                int y = __shfl_up(x, off, 64);
                if (lane >= off) x += y;
            }
            scR[t] = x;
        }
        __syncthreads();
        if (t >= 64 && t < DMAX) scR[t] += scR[63];
        __syncthreads();
#pragma unroll
        for (int k = 0; k < 3; ++k)
            if (lr3[k] >= 0) stage[(scR[lr3[k]] - histR[lr3[k]]) + rk3[k]] = pk3[k];
        __syncthreads();

        for (int r = g; r < nrows; r += 32) {
            int e = scR[r], s = e - histR[r];
            if (s >= e) continue;
            float4 a = {0.0f, 0.0f, 0.0f, 0.0f};
#pragma unroll 2
            for (int j = s; j < e; ++j) {
                unsigned long long p = stage[j];
                int c = (int)(p & 8191);
                float vv = __uint_as_float((unsigned)(p >> 32));
                const float4 w = *(const float4*)(weight + (c << 6) + (fq << 2));
                a.x = fmaf(vv, w.x, a.x);
                a.y = fmaf(vv, w.y, a.y);
                a.z = fmaf(vv, w.z, a.z);
                a.w = fmaf(vv, w.w, a.w);
            }
            float4* ap = (float4*)&acc[(r << 6) + (fq << 2)];
            float4 o = *ap;
            o.x += a.x; o.y += a.y; o.z += a.z; o.w += a.w;
            *ap = o;
        }
        __syncthreads();
    }

    for (int i = t; i < (nrows << 6); i += SP_T)
        out[((long long)row0 << 6) + i] = acc[i] + bias[i & 63];
}

extern "C" void kernel_launch(void* const* d_in, const int* in_sizes, int n_in,
                              void* d_out, int out_size, void* d_ws, size_t ws_size,
                              hipStream_t stream) {
    const int*   index  = (const int*)d_in[0];
    const float* value  = (const float*)d_in[1];
    const float* weight = (const float*)d_in[3];
    const float* bias   = (const float*)d_in[4];
    float*       out    = (float*)d_out;

    int nnz = in_sizes[0] / 2;
    int n   = out_size / 64;
    const int* rows = index;
    const int* cols = index + nnz;

    int d = (n + NBF - 1) / NBF;  // 98 for n=100000 (<= DMAX)
    unsigned M = 0;
    int S = 0;
    for (S = 20; S <= 40; ++S) {
        unsigned long long m = ((1ull << S) + (unsigned)d - 1) / (unsigned)d;
        unsigned long long e = m * (unsigned long long)d - (1ull << S);
        if (m <= 0xffffffffull && e * (unsigned long long)(n > 0 ? n - 1 : 0) < (1ull << S)) {
            M = (unsigned)m;
            break;
        }
    }

    int nChunks = (nnz + CH - 1) / CH;
    char* ws = (char*)d_ws;
    int* fineBase = (int*)ws;                 // 8 KB reserved
    int* cursorF  = (int*)(ws + (8 << 10));   // 4 KB
    int* gcnt     = (int*)(ws + (12 << 10));  // 4 KB
    size_t offC = 64 << 10;
    size_t szC  = (((size_t)nChunks * 64 * 4) + 255) & ~(size_t)255;
    size_t offO = offC + szC;                 // blockOffC
    size_t offF = offO + szC;                 // hist2dF
    size_t szF  = (((size_t)nChunks * NBF * 4) + 255) & ~(size_t)255;
    size_t offP1 = offF + szF;
    size_t szP   = (((size_t)nnz * 8) + 255) & ~(size_t)255;
    size_t offP2 = offP1 + szP;
    int* hist2dC   = (int*)(ws + offC);
    int* blockOffC = (int*)(ws + offO);
    int* hist2dF   = (int*)(ws + offF);
    unsigned long long* pairs1 = (unsigned long long*)(ws + offP1);
    unsigned long long* pairs2 = (unsigned long long*)(ws + offP2);
    unsigned long long* pairs3 = (unsigned long long*)(ws + offC);  // path3 overlay

    bool two = ws_size >= offP2 + szP;
    bool dir = !two && ws_size >= offP1 + szP;

    k_zero1024<<<1, 1024, 0, stream>>>(gcnt);
    size_t smem = (size_t)d * 64 * sizeof(float);
    if (two || dir) {
        kA_hist<<<nChunks, 512, 0, stream>>>(rows, nnz, M, S, hist2dF, hist2dC);
        kB1_reduce<<<64, 1024, 0, stream>>>(hist2dF, nChunks, gcnt);
        kB2_scan<<<1, 1024, 0, stream>>>(gcnt, fineBase, cursorF);
        if (two) {
            kB3_off<<<64, 1024, 0, stream>>>(hist2dC, nChunks, fineBase, blockOffC);
            kC_bin1<<<nChunks, 512, 0, stream>>>(rows, cols, value, nnz, M, S, d,
                                                 blockOffC, pairs1);
            kD_bin2<<<nChunks, 1024, 0, stream>>>(pairs1, nnz, cursorF, pairs2);
            k_spmm4<<<NBF, SP_T, smem, stream>>>(pairs2, fineBase, weight, bias, out, d, n);
        } else {
            k_bin_direct<<<nChunks, 1024, 0, stream>>>(rows, cols, value, nnz, M, S, d,
                                                       cursorF, pairs1);
            k_spmm4<<<NBF, SP_T, smem, stream>>>(pairs1, fineBase, weight, bias, out, d, n);
        }
    } else {
        k_ghist<<<256, 512, 0, stream>>>(rows, nnz, M, S, gcnt);
        kB2_scan<<<1, 1024, 0, stream>>>(gcnt, fineBase, cursorF);
        k_bin_direct<<<nChunks, 1024, 0, stream>>>(rows, cols, value, nnz, M, S, d,
                                                   cursorF, pairs3);
        k_spmm4<<<NBF, SP_T, smem, stream>>>(pairs3, fineBase, weight, bias, out, d, n);
    }
}

// Round 9
// 186.685 us; speedup vs baseline: 2.2667x; 1.0120x over previous
//
#include <hip/hip_runtime.h>

// out[r,f] = bias[f] + sum_{i: rows[i]==r} value[i] * weight[cols[i], f]
// Pipeline: per-chunk histograms (kA) -> reduce (kB1) -> fused scan + offsets
// (kB_off) -> atomic-free coarse bin (kC) -> fine bin with 64-wide window
// keys (kD) -> per-bucket LDS sort + 4-wide batched register-FMA consumer.
// R8 post-mortem: kD crashed — window base must be COARSE-ALIGNED
// ((fFirst>>4)<<4), since pairs1 is only coarse-sorted; taking the first
// element's fine id allowed negative window keys -> LDS corruption -> fault.
//
// pair pack (u64): val[63:32] | fine[29:20] | lr[19:13] | col[12:0]

#define NBF 1024
#define DMAX 128     // lr 7 bits => d <= 128 (n <= 131072)
#define CH 4096      // binning chunk (kA, kC, kD)
#define CC 1536      // consumer sort chunk
#define SP_T 512

__global__ void k_zero1024(int* __restrict__ p) { p[threadIdx.x] = 0; }

// Per-chunk fine (1024) + coarse (64) histograms, per-block writes.
// Chunk mapping MUST match kC_bin1.
__global__ __launch_bounds__(512) void kA_hist(const int* __restrict__ rows, int nnz,
        unsigned M, int S, int* __restrict__ hist2dF, int* __restrict__ hist2dC) {
    __shared__ int h[NBF];
    int t = threadIdx.x, blk = blockIdx.x;
    long long base = (long long)blk * CH;
    int count = (int)min((long long)CH, (long long)nnz - base);
    h[t] = 0; h[t + 512] = 0;
    __syncthreads();
#pragma unroll
    for (int k = 0; k < 8; ++k) {
        int i = t + (k << 9);
        if (i < count) {
            unsigned r = (unsigned)rows[base + i];
            int f = (int)(((unsigned long long)r * M) >> S);
            atomicAdd(&h[f], 1);
        }
    }
    __syncthreads();
    hist2dF[blk * NBF + t] = h[t];
    hist2dF[blk * NBF + 512 + t] = h[t + 512];
    if (t < 64) {
        int s = 0;
#pragma unroll
        for (int j = 0; j < 16; ++j) s += h[(t << 4) + j];
        hist2dC[(blk << 6) + t] = s;
    }
}

// Parallel column-reduce hist2dF -> gcnt.
__global__ __launch_bounds__(1024) void kB1_reduce(const int* __restrict__ hist2dF,
        int nChunks, int* __restrict__ gcnt) {
    int t = threadIdx.x;
    int s = 0;
    for (int b = blockIdx.x; b < nChunks; b += gridDim.x) s += hist2dF[b * NBF + t];
    if (s) atomicAdd(&gcnt[t], s);
}

// Fused: every block scans gcnt (cheap, redundant); block 0 emits fineBase +
// cursorF; if doOff, block c also scans hist2dC[:,c] over the chunk axis.
__global__ __launch_bounds__(1024) void kB_off(const int* __restrict__ gcnt,
        const int* __restrict__ hist2dC, int nChunks, int* __restrict__ fineBase,
        int* __restrict__ cursorF, int* __restrict__ blockOffC, int doOff) {
    __shared__ int sE[NBF];
    __shared__ int wsum[16];
    __shared__ int totalSh;
    int t = threadIdx.x, lane = t & 63, wv = t >> 6;
    int v = gcnt[t];
    int x = v;
#pragma unroll
    for (int off = 1; off < 64; off <<= 1) {
        int y = __shfl_up(x, off, 64);
        if (lane >= off) x += y;
    }
    if (lane == 63) wsum[wv] = x;
    __syncthreads();
    if (t < 16) {
        int s = wsum[t], xs = s;
#pragma unroll
        for (int off = 1; off < 16; off <<= 1) {
            int y = __shfl_up(xs, off, 16);
            if (t >= off) xs += y;
        }
        wsum[t] = xs - s;
    }
    __syncthreads();
    int incl = x + wsum[wv], excl = incl - v;
    sE[t] = excl;
    if (blockIdx.x == 0) {
        fineBase[t] = excl;
        cursorF[t] = excl;
        if (t == NBF - 1) fineBase[NBF] = incl;
    }
    __syncthreads();
    if (!doOff) return;
    int c = blockIdx.x;
    int carry = sE[c << 4];
    for (int b2 = 0; b2 < nChunks; b2 += 1024) {
        int idx = b2 + t;
        int hv = (idx < nChunks) ? hist2dC[(idx << 6) + c] : 0;
        int hx = hv;
#pragma unroll
        for (int off = 1; off < 64; off <<= 1) {
            int y = __shfl_up(hx, off, 64);
            if (lane >= off) hx += y;
        }
        if (lane == 63) wsum[wv] = hx;
        __syncthreads();
        if (t < 16) {
            int s = wsum[t], xs = s;
#pragma unroll
            for (int off = 1; off < 16; off <<= 1) {
                int y = __shfl_up(xs, off, 16);
                if (t >= off) xs += y;
            }
            wsum[t] = xs - s;
        }
        __syncthreads();
        int hincl = hx + wsum[wv];
        if (idx < nChunks) blockOffC[(idx << 6) + c] = carry + hincl - hv;
        if (t == 1023) totalSh = hincl;
        __syncthreads();
        carry += totalSh;
    }
}

// Path3 fallback: grid-stride fine histogram with global atomics.
__global__ void k_ghist(const int* __restrict__ rows, int nnz, unsigned M, int S,
                        int* __restrict__ gcnt) {
    __shared__ int h[NBF];
    int t = threadIdx.x;
    for (int i = t; i < NBF; i += blockDim.x) h[i] = 0;
    __syncthreads();
    for (int i = blockIdx.x * blockDim.x + t; i < nnz; i += gridDim.x * blockDim.x) {
        unsigned r = (unsigned)rows[i];
        int f = (int)(((unsigned long long)r * M) >> S);
        atomicAdd(&h[f], 1);
    }
    __syncthreads();
    for (int i = t; i < NBF; i += blockDim.x)
        if (h[i]) atomicAdd(&gcnt[i], h[i]);
}

// Coarse bin, atomic-free: dest base from precomputed blockOffC. Runs ~512 B.
__global__ __launch_bounds__(512) void kC_bin1(const int* __restrict__ rows,
        const int* __restrict__ cols, const float* __restrict__ vals, int nnz,
        unsigned M, int S, int d, const int* __restrict__ blockOffC,
        unsigned long long* __restrict__ pairs1) {
    __shared__ unsigned long long stage[CH];  // 32 KB
    __shared__ int histC[64], scC[64], adjC[64];
    int t = threadIdx.x, blk = blockIdx.x;
    long long base = (long long)blk * CH;
    int count = (int)min((long long)CH, (long long)nnz - base);
    if (t < 64) histC[t] = 0;
    __syncthreads();
    int cs8[8], rk8[8];
    unsigned long long pk8[8];
#pragma unroll
    for (int k = 0; k < 8; ++k) {
        int i = t + (k << 9);
        cs8[k] = -1;
        if (i < count) {
            unsigned r = (unsigned)rows[base + i];
            int c = cols[base + i];
            float v = vals[base + i];
            int f = (int)(((unsigned long long)r * M) >> S);
            int lr = (int)r - f * d;
            int cs = f >> 4;
            cs8[k] = cs;
            rk8[k] = atomicAdd(&histC[cs], 1);
            pk8[k] = ((unsigned long long)__float_as_uint(v) << 32) |
                     ((unsigned)f << 20) | ((unsigned)lr << 13) | (unsigned)c;
        }
    }
    __syncthreads();
    if (t < 64) {
        int v = histC[t], x = v;
#pragma unroll
        for (int off = 1; off < 64; off <<= 1) {
            int y = __shfl_up(x, off, 64);
            if (t >= off) x += y;
        }
        scC[t] = x;
        adjC[t] = blockOffC[(blk << 6) + t] - (x - v);
    }
    __syncthreads();
#pragma unroll
    for (int k = 0; k < 8; ++k)
        if (cs8[k] >= 0) stage[(scC[cs8[k]] - histC[cs8[k]]) + rk8[k]] = pk8[k];
    __syncthreads();
    for (int i = t; i < count; i += 512) {
        unsigned long long p = stage[i];
        int cs = (int)((p >> 24) & 63);
        pairs1[adjC[cs] + i] = p;
    }
}

// Fine bin from coarse-sorted pairs. Window base f0 = coarse-aligned floor of
// the FIRST element's fine id: coarse-sorted order guarantees every fine id
// in the chunk is >= cFirst*16 (fine order WITHIN a coarse run is arbitrary —
// taking fFirst itself was R8's OOB crash). Span check: fLast < f0+64
// (chunk spans <= 4 coarse buckets; typically <= 2 since runs ~62k >> 4096).
__global__ __launch_bounds__(1024) void kD_bin2(const unsigned long long* __restrict__ pairs1,
        int nnz, int* __restrict__ cursorF, unsigned long long* __restrict__ pairs2) {
    __shared__ unsigned long long stage[CH];  // 32 KB
    __shared__ int histW[64], scW[64], adjW[64];
    __shared__ int f0sh;
    int t = threadIdx.x;
    long long base = (long long)blockIdx.x * CH;
    int count = (int)min((long long)CH, (long long)nnz - base);
    if (t == 0) {
        int fFirst = (int)((pairs1[base] >> 20) & 1023);
        int fLast  = (int)((pairs1[base + count - 1] >> 20) & 1023);
        int f0 = (fFirst >> 4) << 4;          // coarse-aligned lower bound
        f0sh = (fLast < f0 + 64) ? f0 : -1;
    }
    if (t < 64) histW[t] = 0;
    __syncthreads();
    int f0 = f0sh;
    if (f0 < 0) {
        // slow path: per-pair scatter (correct for arbitrary span)
#pragma unroll
        for (int k = 0; k < 4; ++k) {
            int i = t + (k << 10);
            if (i < count) {
                unsigned long long p = pairs1[base + i];
                int f = (int)((p >> 20) & 1023);
                int pos = atomicAdd(&cursorF[f], 1);
                pairs2[pos] = p;
            }
        }
        return;
    }
    int k4[4], rk4[4];
    unsigned long long pk4[4];
#pragma unroll
    for (int k = 0; k < 4; ++k) {
        int i = t + (k << 10);
        k4[k] = -1;
        if (i < count) {
            unsigned long long p = pairs1[base + i];
            int kf = (int)((p >> 20) & 1023) - f0;
            k4[k] = kf;
            rk4[k] = atomicAdd(&histW[kf], 1);
            pk4[k] = p;
        }
    }
    __syncthreads();
    if (t < 64) {  // wave 0: 64-wide shfl scan
        int v = histW[t], x = v;
#pragma unroll
        for (int off = 1; off < 64; off <<= 1) {
            int y = __shfl_up(x, off, 64);
            if (t >= off) x += y;
        }
        scW[t] = x;
        if (v > 0) {
            int g = atomicAdd(&cursorF[f0 + t], v);
            adjW[t] = g - (x - v);
        }
    }
    __syncthreads();
#pragma unroll
    for (int k = 0; k < 4; ++k)
        if (k4[k] >= 0) stage[(scW[k4[k]] - histW[k4[k]]) + rk4[k]] = pk4[k];
    __syncthreads();
    for (int i = t; i < count; i += 1024) {
        unsigned long long p = stage[i];
        int kf = (int)((p >> 20) & 1023) - f0;
        pairs2[adjW[kf] + i] = p;
    }
}

// Fallback direct fine bin: source -> fine buckets, cursorF atomics.
__global__ __launch_bounds__(1024) void k_bin_direct(const int* __restrict__ rows,
        const int* __restrict__ cols, const float* __restrict__ vals, int nnz,
        unsigned M, int S, int d, int* __restrict__ cursorF,
        unsigned long long* __restrict__ pairs1) {
    __shared__ unsigned long long stage[CH];
    __shared__ int histF[NBF], scF[NBF], adjF[NBF];
    __shared__ int wsum[16];
    int t = threadIdx.x, lane = t & 63, wv = t >> 6;
    long long base = (long long)blockIdx.x * CH;
    int count = (int)min((long long)CH, (long long)nnz - base);
    histF[t] = 0;
    __syncthreads();
    int f4[4], rk4[4];
    unsigned long long pk4[4];
#pragma unroll
    for (int k = 0; k < 4; ++k) {
        int i = t + (k << 10);
        f4[k] = -1;
        if (i < count) {
            unsigned r = (unsigned)rows[base + i];
            int c = cols[base + i];
            float vv = vals[base + i];
            int f = (int)(((unsigned long long)r * M) >> S);
            int lr = (int)r - f * d;
            f4[k] = f;
            rk4[k] = atomicAdd(&histF[f], 1);
            pk4[k] = ((unsigned long long)__float_as_uint(vv) << 32) |
                     ((unsigned)f << 20) | ((unsigned)lr << 13) | (unsigned)c;
        }
    }
    __syncthreads();
    int v = histF[t], x = v;
#pragma unroll
    for (int off = 1; off < 64; off <<= 1) {
        int y = __shfl_up(x, off, 64);
        if (lane >= off) x += y;
    }
    if (lane == 63) wsum[wv] = x;
    __syncthreads();
    if (t < 16) {
        int s = wsum[t], xs = s;
#pragma unroll
        for (int off = 1; off < 16; off <<= 1) {
            int y = __shfl_up(xs, off, 16);
            if (t >= off) xs += y;
        }
        wsum[t] = xs - s;
    }
    __syncthreads();
    int incl = x + wsum[wv];
    scF[t] = incl;
    if (v > 0) {
        int g = atomicAdd(&cursorF[t], v);
        adjF[t] = g - (incl - v);
    }
    __syncthreads();
#pragma unroll
    for (int k = 0; k < 4; ++k)
        if (f4[k] >= 0) stage[(scF[f4[k]] - histF[f4[k]]) + rk4[k]] = pk4[k];
    __syncthreads();
    for (int i = t; i < count; i += 1024) {
        unsigned long long p = stage[i];
        int f = (int)((p >> 20) & 1023);
        pairs1[adjF[f] + i] = p;
    }
}

// Consumer: one block per fine bucket, 38.4 KB LDS => 4 blocks/CU. Sort chunk
// by local row (int LDS atomics + shfl scan), then 16-lane groups walk whole
// rows with 4-wide batched weight loads (4 independent dwordx4 in flight).
__global__ __launch_bounds__(SP_T, 8) void k_spmm5(
        const unsigned long long* __restrict__ pairs, const int* __restrict__ fineBase,
        const float* __restrict__ weight, const float* __restrict__ bias,
        float* __restrict__ out, int d, int n) {
    __shared__ unsigned long long stage[CC];   // 12 KB
    __shared__ int histR[DMAX], scR[DMAX];     // 1 KB
    extern __shared__ float acc[];             // d*64 floats (25 KB @ d=98)
    int b = blockIdx.x, t = threadIdx.x;
    int row0 = b * d;
    if (row0 >= n) return;
    int nrows = min(d, n - row0);
    int start = fineBase[b], end = fineBase[b + 1];

    for (int i = t; i < (nrows << 6); i += SP_T) acc[i] = 0.0f;

    int g = t >> 4, fq = t & 15;
    for (int cb = start; cb < end; cb += CC) {
        int cnt = min(CC, end - cb);
        if (t < DMAX) histR[t] = 0;
        __syncthreads();
        int lr3[3], rk3[3];
        unsigned long long pk3[3];
#pragma unroll
        for (int k = 0; k < 3; ++k) {
            int i = t + (k << 9);
            lr3[k] = -1;
            if (i < cnt) {
                unsigned long long p = pairs[cb + i];
                int lr = (int)((p >> 13) & 127);
                lr3[k] = lr;
                rk3[k] = atomicAdd(&histR[lr], 1);
                pk3[k] = p;
            }
        }
        __syncthreads();
        if (t < DMAX) {
            int v = histR[t], x = v;
            int lane = t & 63;
#pragma unroll
            for (int off = 1; off < 64; off <<= 1) {
                int y = __shfl_up(x, off, 64);
                if (lane >= off) x += y;
            }
            scR[t] = x;
        }
        __syncthreads();
        if (t >= 64 && t < DMAX) scR[t] += scR[63];
        __syncthreads();
#pragma unroll
        for (int k = 0; k < 3; ++k)
            if (lr3[k] >= 0) stage[(scR[lr3[k]] - histR[lr3[k]]) + rk3[k]] = pk3[k];
        __syncthreads();

        for (int r = g; r < nrows; r += 32) {
            int e = scR[r], s = e - histR[r];
            if (s >= e) continue;
            float4 a = {0.0f, 0.0f, 0.0f, 0.0f};
            int j = s;
            for (; j + 4 <= e; j += 4) {
                unsigned long long p0 = stage[j + 0];
                unsigned long long p1 = stage[j + 1];
                unsigned long long p2 = stage[j + 2];
                unsigned long long p3 = stage[j + 3];
                const float4 w0 = *(const float4*)(weight + (((int)(p0 & 8191)) << 6) + (fq << 2));
                const float4 w1 = *(const float4*)(weight + (((int)(p1 & 8191)) << 6) + (fq << 2));
                const float4 w2 = *(const float4*)(weight + (((int)(p2 & 8191)) << 6) + (fq << 2));
                const float4 w3 = *(const float4*)(weight + (((int)(p3 & 8191)) << 6) + (fq << 2));
                float v0 = __uint_as_float((unsigned)(p0 >> 32));
                float v1 = __uint_as_float((unsigned)(p1 >> 32));
                float v2 = __uint_as_float((unsigned)(p2 >> 32));
                float v3 = __uint_as_float((unsigned)(p3 >> 32));
                a.x = fmaf(v0, w0.x, a.x); a.y = fmaf(v0, w0.y, a.y);
                a.z = fmaf(v0, w0.z, a.z); a.w = fmaf(v0, w0.w, a.w);
                a.x = fmaf(v1, w1.x, a.x); a.y = fmaf(v1, w1.y, a.y);
                a.z = fmaf(v1, w1.z, a.z); a.w = fmaf(v1, w1.w, a.w);
                a.x = fmaf(v2, w2.x, a.x); a.y = fmaf(v2, w2.y, a.y);
                a.z = fmaf(v2, w2.z, a.z); a.w = fmaf(v2, w2.w, a.w);
                a.x = fmaf(v3, w3.x, a.x); a.y = fmaf(v3, w3.y, a.y);
                a.z = fmaf(v3, w3.z, a.z); a.w = fmaf(v3, w3.w, a.w);
            }
            for (; j < e; ++j) {
                unsigned long long p = stage[j];
                float vv = __uint_as_float((unsigned)(p >> 32));
                const float4 w = *(const float4*)(weight + (((int)(p & 8191)) << 6) + (fq << 2));
                a.x = fmaf(vv, w.x, a.x); a.y = fmaf(vv, w.y, a.y);
                a.z = fmaf(vv, w.z, a.z); a.w = fmaf(vv, w.w, a.w);
            }
            float4* ap = (float4*)&acc[(r << 6) + (fq << 2)];
            float4 o = *ap;
            o.x += a.x; o.y += a.y; o.z += a.z; o.w += a.w;
            *ap = o;
        }
        __syncthreads();
    }

    for (int i = t; i < (nrows << 6); i += SP_T)
        out[((long long)row0 << 6) + i] = acc[i] + bias[i & 63];
}

extern "C" void kernel_launch(void* const* d_in, const int* in_sizes, int n_in,
                              void* d_out, int out_size, void* d_ws, size_t ws_size,
                              hipStream_t stream) {
    const int*   index  = (const int*)d_in[0];
    const float* value  = (const float*)d_in[1];
    const float* weight = (const float*)d_in[3];
    const float* bias   = (const float*)d_in[4];
    float*       out    = (float*)d_out;

    int nnz = in_sizes[0] / 2;
    int n   = out_size / 64;
    const int* rows = index;
    const int* cols = index + nnz;

    int d = (n + NBF - 1) / NBF;  // 98 for n=100000 (<= DMAX)
    unsigned M = 0;
    int S = 0;
    for (S = 20; S <= 40; ++S) {
        unsigned long long m = ((1ull << S) + (unsigned)d - 1) / (unsigned)d;
        unsigned long long e = m * (unsigned long long)d - (1ull << S);
        if (m <= 0xffffffffull && e * (unsigned long long)(n > 0 ? n - 1 : 0) < (1ull << S)) {
            M = (unsigned)m;
            break;
        }
    }

    int nChunks = (nnz + CH - 1) / CH;
    char* ws = (char*)d_ws;
    int* fineBase = (int*)ws;                 // 8 KB reserved
    int* cursorF  = (int*)(ws + (8 << 10));   // 4 KB
    int* gcnt     = (int*)(ws + (12 << 10));  // 4 KB
    size_t offC = 64 << 10;
    size_t szC  = (((size_t)nChunks * 64 * 4) + 255) & ~(size_t)255;
    size_t offO = offC + szC;                 // blockOffC
    size_t offF = offO + szC;                 // hist2dF
    size_t szF  = (((size_t)nChunks * NBF * 4) + 255) & ~(size_t)255;
    size_t offP1 = offF + szF;
    size_t szP   = (((size_t)nnz * 8) + 255) & ~(size_t)255;
    size_t offP2 = offP1 + szP;
    int* hist2dC   = (int*)(ws + offC);
    int* blockOffC = (int*)(ws + offO);
    int* hist2dF   = (int*)(ws + offF);
    unsigned long long* pairs1 = (unsigned long long*)(ws + offP1);
    unsigned long long* pairs2 = (unsigned long long*)(ws + offP2);
    unsigned long long* pairs3 = (unsigned long long*)(ws + offC);  // path3 overlay

    bool two = ws_size >= offP2 + szP;
    bool dir = !two && ws_size >= offP1 + szP;

    k_zero1024<<<1, 1024, 0, stream>>>(gcnt);
    size_t smem = (size_t)d * 64 * sizeof(float);
    if (two || dir) {
        kA_hist<<<nChunks, 512, 0, stream>>>(rows, nnz, M, S, hist2dF, hist2dC);
        kB1_reduce<<<64, 1024, 0, stream>>>(hist2dF, nChunks, gcnt);
        if (two) {
            kB_off<<<64, 1024, 0, stream>>>(gcnt, hist2dC, nChunks, fineBase, cursorF,
                                            blockOffC, 1);
            kC_bin1<<<nChunks, 512, 0, stream>>>(rows, cols, value, nnz, M, S, d,
                                                 blockOffC, pairs1);
            kD_bin2<<<nChunks, 1024, 0, stream>>>(pairs1, nnz, cursorF, pairs2);
            k_spmm5<<<NBF, SP_T, smem, stream>>>(pairs2, fineBase, weight, bias, out, d, n);
        } else {
            kB_off<<<1, 1024, 0, stream>>>(gcnt, hist2dC, nChunks, fineBase, cursorF,
                                           blockOffC, 0);
            k_bin_direct<<<nChunks, 1024, 0, stream>>>(rows, cols, value, nnz, M, S, d,
                                                       cursorF, pairs1);
            k_spmm5<<<NBF, SP_T, smem, stream>>>(pairs1, fineBase, weight, bias, out, d, n);
        }
    } else {
        k_ghist<<<256, 512, 0, stream>>>(rows, nnz, M, S, gcnt);
        kB_off<<<1, 1024, 0, stream>>>(gcnt, hist2dC, nChunks, fineBase, cursorF,
                                       blockOffC, 0);
        k_bin_direct<<<nChunks, 1024, 0, stream>>>(rows, cols, value, nnz, M, S, d,
                                                   cursorF, pairs3);
        k_spmm5<<<NBF, SP_T, smem, stream>>>(pairs3, fineBase, weight, bias, out, d, n);
    }
}